// Round 4
// baseline (71.831 us; speedup 1.0000x reference)
//
#include <hip/hip_runtime.h>

#define NN   30000
#define NCTX 32
#define FIN  256
#define HID  128

typedef short short8 __attribute__((ext_vector_type(8)));
typedef float f32x4  __attribute__((ext_vector_type(4)));

__device__ __forceinline__ unsigned short f2b(float x) {
    union { float f; unsigned u; } v; v.f = x;
    unsigned r = v.u + 0x7FFFu + ((v.u >> 16) & 1u);   // RTNE
    return (unsigned short)(r >> 16);
}
__device__ __forceinline__ float b2f(unsigned short u) {
    union { unsigned u; float f; } v; v.u = ((unsigned)u) << 16;
    return v.f;
}

// Pack W_j into MFMA B-fragment order (split bf16 hi/lo); block 64 computes
// vi[f] = sum_h W_i[f][h]*a_w[h].
__global__ __launch_bounds__(64) void k_pack(const float* __restrict__ Wj,
                                             const float* __restrict__ Wi,
                                             const float* __restrict__ aw,
                                             short8* __restrict__ whi,
                                             short8* __restrict__ wlo,
                                             float* __restrict__ vi) {
    const int b = blockIdx.x;
    const int l = threadIdx.x;
    if (b == 64) {
        #pragma unroll
        for (int i = 0; i < 4; ++i) {
            const int f = l * 4 + i;
            float s = 0.f;
            #pragma unroll 8
            for (int h = 0; h < HID; ++h) s += Wi[f * HID + h] * aw[h];
            vi[f] = s;
        }
        return;
    }
    const int s = b >> 3, t = b & 7;
    const int kbase = s * 32 + (l >> 4) * 8;
    const int c = t * 16 + (l & 15);
    short8 hi, lo;
    #pragma unroll
    for (int j = 0; j < 8; ++j) {
        const float w = Wj[(long)(kbase + j) * HID + c];
        const unsigned short h = f2b(w);
        hi[j] = (short)h;
        lo[j] = (short)f2b(w - b2f(h));
    }
    whi[b * 64 + l] = hi;
    wlo[b * 64 + l] = lo;
}

// Fused: Wh = h_i @ W_j (MFMA, split-bf16), si = h_i.vi + ab, sj = Wh.a_w[128:]
// Wh is stored as two column-split half-tables (cols 0-63 / 64-127), bf16.
__global__ __launch_bounds__(256) void k_gemm(const float* __restrict__ hin,
                                              const short8* __restrict__ whi,
                                              const short8* __restrict__ wlo,
                                              const float* __restrict__ vi,
                                              const float* __restrict__ aw,
                                              const float* __restrict__ ab,
                                              unsigned short* __restrict__ Wh0,
                                              unsigned short* __restrict__ Wh1,
                                              float* __restrict__ sib,
                                              float* __restrict__ sjv) {
    const int tid  = threadIdx.x;
    const int l    = tid & 63;
    const int wave = blockIdx.x * 4 + (tid >> 6);
    if (wave >= NN / 16) return;
    const long rowbase = (long)wave * 16;
    const int r  = l & 15;    // A row / D col-within-tile
    const int kg = l >> 4;    // k-group

    const float* hrow = hin + (rowbase + r) * FIN + kg * 8;
    const float* vip  = vi + kg * 8;

    f32x4 acc[8];
    #pragma unroll
    for (int t = 0; t < 8; ++t) acc[t] = (f32x4){0.f, 0.f, 0.f, 0.f};
    float si = 0.f;

    #pragma unroll 2
    for (int s = 0; s < 8; ++s) {
        const float4 ha = *(const float4*)(hrow + s * 32);
        const float4 hb = *(const float4*)(hrow + s * 32 + 4);
        const float4 va = *(const float4*)(vip + s * 32);
        const float4 vb = *(const float4*)(vip + s * 32 + 4);
        const float hv[8] = {ha.x, ha.y, ha.z, ha.w, hb.x, hb.y, hb.z, hb.w};
        const float vv[8] = {va.x, va.y, va.z, va.w, vb.x, vb.y, vb.z, vb.w};
        short8 ahi, alo;
        #pragma unroll
        for (int j = 0; j < 8; ++j) {
            si += hv[j] * vv[j];
            const unsigned short hb16 = f2b(hv[j]);
            ahi[j] = (short)hb16;
            alo[j] = (short)f2b(hv[j] - b2f(hb16));
        }
        #pragma unroll
        for (int t = 0; t < 8; ++t) {
            const short8 bh = whi[(s * 8 + t) * 64 + l];
            const short8 bl = wlo[(s * 8 + t) * 64 + l];
            acc[t] = __builtin_amdgcn_mfma_f32_16x16x32_bf16(ahi, bh, acc[t], 0, 0, 0);
            acc[t] = __builtin_amdgcn_mfma_f32_16x16x32_bf16(alo, bh, acc[t], 0, 0, 0);
            acc[t] = __builtin_amdgcn_mfma_f32_16x16x32_bf16(ahi, bl, acc[t], 0, 0, 0);
        }
    }

    si += __shfl_xor(si, 16);
    si += __shfl_xor(si, 32);
    if (l < 16) sib[rowbase + l] = si + ab[0];

    float aw2v[8];
    #pragma unroll
    for (int t = 0; t < 8; ++t) aw2v[t] = aw[HID + t * 16 + r];
    #pragma unroll
    for (int j = 0; j < 4; ++j) {
        float p = 0.f;
        #pragma unroll
        for (int t = 0; t < 8; ++t) p += acc[t][j] * aw2v[t];
        p += __shfl_xor(p, 1); p += __shfl_xor(p, 2);
        p += __shfl_xor(p, 4); p += __shfl_xor(p, 8);
        if (r == 0) sjv[rowbase + kg * 4 + j] = p;
    }

    #pragma unroll
    for (int j = 0; j < 4; ++j) {
        const long rr = rowbase + kg * 4 + j;
        #pragma unroll
        for (int t = 0; t < 4; ++t)
            Wh0[rr * 64 + t * 16 + r] = f2b(acc[t][j]);
        #pragma unroll
        for (int t = 4; t < 8; ++t)
            Wh1[rr * 64 + (t - 4) * 16 + r] = f2b(acc[t][j]);
    }
}

// One column-half pass: softmax (recomputed) + gather-aggregate from a
// 3.84 MB L2-resident half-table. 2 nodes per wave; one 128-B row per
// 8 lanes -> 8 independent 16-B loads in flight per wave.
__global__ __launch_bounds__(256) void k_attn_half(const int* __restrict__ ctx,
                                                   const unsigned short* __restrict__ Whp,
                                                   const float* __restrict__ sib,
                                                   const float* __restrict__ sjv,
                                                   float* __restrict__ out,
                                                   int p) {
    const int lane = threadIdx.x & 63;
    const int wid  = threadIdx.x >> 6;
    const long nb  = (long)blockIdx.x * 8 + wid * 2;
    const int h    = lane >> 5;          // which of the 2 nodes
    const long n   = nb + h;
    const int c    = lane & 31;

    const int idx = ctx[n * NCTX + c];
    const int icl = (idx >= 0) ? idx : 0;
    float s;
    if (idx >= 0) {
        s = sib[n] + sjv[icl];
        s = (s >= 0.f) ? s : 0.2f * s;
    } else {
        s = -9e15f;
    }
    float mx = s;
    #pragma unroll
    for (int m = 16; m >= 1; m >>= 1) mx = fmaxf(mx, __shfl_xor(mx, m));
    const float e = __expf(s - mx);
    float sum = e;
    #pragma unroll
    for (int m = 16; m >= 1; m >>= 1) sum += __shfl_xor(sum, m);
    const float at = (idx >= 0) ? e / sum : 0.f;

    const int r  = (lane >> 3) & 3;   // row-slot within node
    const int cl = lane & 7;          // 16-B chunk within the 128-B half-row

    float a0 = 0.f, a1 = 0.f, a2 = 0.f, a3 = 0.f, a4 = 0.f, a5 = 0.f, a6 = 0.f, a7 = 0.f;
    #pragma unroll
    for (int it = 0; it < 8; ++it) {
        const int   src = (lane & 32) | (it * 4 + r);
        const float w   = __shfl(at, src);
        const int   ic  = __shfl(icl, src);
        const uint4 pv  = *(const uint4*)(Whp + (long)ic * 64 + cl * 8);
        a0 += w * b2f((unsigned short)(pv.x & 0xFFFFu));
        a1 += w * b2f((unsigned short)(pv.x >> 16));
        a2 += w * b2f((unsigned short)(pv.y & 0xFFFFu));
        a3 += w * b2f((unsigned short)(pv.y >> 16));
        a4 += w * b2f((unsigned short)(pv.z & 0xFFFFu));
        a5 += w * b2f((unsigned short)(pv.z >> 16));
        a6 += w * b2f((unsigned short)(pv.w & 0xFFFFu));
        a7 += w * b2f((unsigned short)(pv.w >> 16));
    }
    // reduce over row-slot r (lane bits 3,4)
    #pragma unroll
    for (int m = 8; m <= 16; m <<= 1) {
        a0 += __shfl_xor(a0, m); a1 += __shfl_xor(a1, m);
        a2 += __shfl_xor(a2, m); a3 += __shfl_xor(a3, m);
        a4 += __shfl_xor(a4, m); a5 += __shfl_xor(a5, m);
        a6 += __shfl_xor(a6, m); a7 += __shfl_xor(a7, m);
    }
    if (r == 0) {
        float4* op = (float4*)(out + n * HID + p * 64 + cl * 8);
        op[0] = (float4){a0, a1, a2, a3};
        op[1] = (float4){a4, a5, a6, a7};
    }
}

extern "C" void kernel_launch(void* const* d_in, const int* in_sizes, int n_in,
                              void* d_out, int out_size, void* d_ws, size_t ws_size,
                              hipStream_t stream) {
    const float* h_i = (const float*)d_in[0];
    const int*   ctx = (const int*)d_in[1];
    const float* W_i = (const float*)d_in[2];
    const float* W_j = (const float*)d_in[3];
    const float* a_w = (const float*)d_in[4];
    const float* a_b = (const float*)d_in[5];
    float* out = (float*)d_out;

    char* ws = (char*)d_ws;
    unsigned short* Wh0 = (unsigned short*)ws;            // N*64 bf16 = 3,840,000 B
    unsigned short* Wh1 = (unsigned short*)(ws + 3840000);// N*64 bf16 = 3,840,000 B
    float* sib = (float*)(ws + 7680000);                  // N f32
    float* sjv = (float*)(ws + 7800000);                  // N f32
    float* vi  = (float*)(ws + 7920000);                  // 256 f32 (16B aligned)
    short8* whi = (short8*)(ws + 7921024);                // 64 KB
    short8* wlo = (short8*)(ws + 7986560);                // 64 KB

    k_pack<<<65, 64, 0, stream>>>(W_j, W_i, a_w, whi, wlo, vi);
    k_gemm<<<(NN / 16 + 3) / 4, 256, 0, stream>>>(h_i, whi, wlo, vi, a_w, a_b,
                                                  Wh0, Wh1, sib, sjv);
    k_attn_half<<<NN / 8, 256, 0, stream>>>(ctx, Wh0, sib, sjv, out, 0);
    k_attn_half<<<NN / 8, 256, 0, stream>>>(ctx, Wh1, sib, sjv, out, 1);
}